// Round 3
// baseline (225.651 us; speedup 1.0000x reference)
//
#include <hip/hip_runtime.h>

// Problem constants (reference: H = W = 2048, C = 8, N = 1e6)
#define HH 2048
#define WW 2048
#define CC 8
#define MODV 2044.0f   // H - 4

typedef float f32x2 __attribute__((ext_vector_type(2)));
typedef float f32x4 __attribute__((ext_vector_type(4)));

// Bilinear combine for 4 channels at once (ext_vector broadcasts scalars).
// Reference naming (follow the code, not the names):
//   tl = V[i0][i1], tr = V[i0+1][i1], bl = V[i0][i1+1], br = V[i0+1][i1+1]
//   mb = br + d0*(bl-br); mt = tr + d0*(tl-tr); out = mb + d1*(mt-mb)
__device__ __forceinline__ f32x4 blerp4(f32x4 tl, f32x4 tr, f32x4 bl, f32x4 br,
                                        float d0, float d1, float m) {
    f32x4 mb = br + d0 * (bl - br);
    f32x4 mt = tr + d0 * (tl - tr);
    return m * (mb + d1 * (mt - mb));
}

// c = (coord - 1) mod 2044 + 1 (floored mod); returns base ptr of V[i0][i1]
__device__ __forceinline__ const float* point_addr(f32x2 co, const float* visible,
                                                   float& d0, float& d1, float& m) {
    float x = co.x - 1.0f;
    float y = co.y - 1.0f;
    float cx = fmodf(x, MODV); if (cx < 0.0f) cx += MODV;
    float cy = fmodf(y, MODV); if (cy < 0.0f) cy += MODV;
    cx += 1.0f;
    cy += 1.0f;
    float fx = floorf(cx);
    float fy = floorf(cy);
    d0 = cx - fx;               // delta along dim 0 (rows)
    d1 = cy - fy;               // delta along dim 1 (cols)
    int i0 = (int)fx;           // row index in [1, 2044]
    int i1 = (int)fy;           // col index in [1, 2044]
    // off = c > dims (unreachable since c < 2045; kept for fidelity)
    m = (cx > (float)HH) ? 0.0f : 1.0f;
    return visible + ((size_t)i0 * WW + (size_t)i1) * CC;
}

// Two points per thread, with the 16 gathers FORCED to stay clustered ahead of
// all uses via sched_barrier(0). Rounds 0-2 showed VGPR_Count 24-28: the
// scheduler was serializing the gathers (a 16-float4 in-flight cluster needs
// 64 VGPRs for destinations alone), so nominal "MLP" never existed in the
// emitted code. The fence forces all 16 destinations simultaneously live;
// verification criterion: VGPR_Count must jump to ~84-100.
// __launch_bounds__(256, 5): min 5 waves/EU -> VGPR budget ~102, occupancy
// cap 62% ~= the 55-67% the HW was already delivering at VGPR 24-28.
__global__ __launch_bounds__(256, 5) void idx2pixel_kernel(
    const float* __restrict__ coords,   // (N, 2)
    const float* __restrict__ visible,  // (H, W, C) row-major
    float* __restrict__ out,            // (N, C)
    int n)
{
    int t = blockIdx.x * blockDim.x + threadIdx.x;
    int half = (n + 1) >> 1;
    if (t >= half) return;
    int tB = t + half;
    bool hB = tB < n;
    int iB = hB ? tB : t;   // clamp masked second point to a safe address

    const f32x2* cp = reinterpret_cast<const f32x2*>(coords);
    f32x2 coA = cp[t];
    f32x2 coB = cp[iB];

    float d0A, d1A, mA, d0B, d1B, mB;
    const float* pA = point_addr(coA, visible, d0A, d1A, mA);
    const float* pB = point_addr(coB, visible, d0B, d1B, mB);
    const size_t RS = (size_t)WW * CC;   // row stride in floats

    // ---- issue all 16 gathers; nothing may sink below the fence ----
    // per row-segment layout: [i1 pixel: 8 floats][i1+1 pixel: 8 floats] = 64B
#define LD8(P, base)                                   \
    f32x4 P##tl0 = *(const f32x4*)(base);              \
    f32x4 P##tl1 = *(const f32x4*)((base) + 4);        \
    f32x4 P##bl0 = *(const f32x4*)((base) + 8);        \
    f32x4 P##bl1 = *(const f32x4*)((base) + 12);       \
    f32x4 P##tr0 = *(const f32x4*)((base) + RS);       \
    f32x4 P##tr1 = *(const f32x4*)((base) + RS + 4);   \
    f32x4 P##br0 = *(const f32x4*)((base) + RS + 8);   \
    f32x4 P##br1 = *(const f32x4*)((base) + RS + 12);

    LD8(A, pA)
    LD8(B, pB)
#undef LD8

    // Scheduling fence: no instruction may cross. Loads stay clustered above
    // (16 outstanding, incremental vmcnt waits below); compiler cannot
    // serialize-and-reuse destination registers.
    __builtin_amdgcn_sched_barrier(0);

    // ---- compute + store in issue order (A's data lands first) ----
    {
        f32x4 o0 = blerp4(Atl0, Atr0, Abl0, Abr0, d0A, d1A, mA);
        f32x4 o1 = blerp4(Atl1, Atr1, Abl1, Abr1, d0A, d1A, mA);
        float* po = out + (size_t)t * CC;
        *(f32x4*)po = o0;
        *(f32x4*)(po + 4) = o1;
    }
    {
        f32x4 o0 = blerp4(Btl0, Btr0, Bbl0, Bbr0, d0B, d1B, mB);
        f32x4 o1 = blerp4(Btl1, Btr1, Bbl1, Bbr1, d0B, d1B, mB);
        if (hB) {
            float* po = out + (size_t)tB * CC;
            *(f32x4*)po = o0;
            *(f32x4*)(po + 4) = o1;
        }
    }
}

extern "C" void kernel_launch(void* const* d_in, const int* in_sizes, int n_in,
                              void* d_out, int out_size, void* d_ws, size_t ws_size,
                              hipStream_t stream) {
    const float* coords  = (const float*)d_in[0];  // (N, 2) fp32
    const float* visible = (const float*)d_in[1];  // (2048, 2048, 8) fp32
    float* out = (float*)d_out;                    // (N, 8) fp32
    int n = in_sizes[0] / 2;

    int half = (n + 1) >> 1;  // 2 points per thread
    int block = 256;
    int grid = (half + block - 1) / block;
    idx2pixel_kernel<<<grid, block, 0, stream>>>(coords, visible, out, n);
}